// Round 3
// baseline (333.522 us; speedup 1.0000x reference)
//
#include <hip/hip_runtime.h>

typedef __bf16 bf16;
typedef __bf16 bf16x4 __attribute__((ext_vector_type(4)));
typedef __bf16 bf16x8 __attribute__((ext_vector_type(8)));
typedef float f32x4 __attribute__((ext_vector_type(4)));

#define DIM   2048
#define BQ    128
#define KVL   4096
#define KVT   4224   // KV_LEN + Q_LEN
#define SCALE 0.022097086912079608f  // 1/sqrt(2048)

// Swizzled element offset inside a [ROWS][64]-bf16 LDS tile (128B rows).
__device__ __forceinline__ int swz(int row, int col) {
  return row * 64 + (col ^ ((row & 7) << 3));
}

// ---- staging: global fp32 [ROWS][ld] -> bf16 LDS tile [ROWS][64] ----
template<int ROWS, int NTHR>
__device__ __forceinline__ void stage_f32(const float* __restrict__ src, int ld,
                                          bf16* dst, int tid) {
  constexpr int ITERS = (ROWS * 16) / NTHR;
  const int r0 = tid >> 4;
  const int c  = (tid & 15) * 4;
  #pragma unroll
  for (int j = 0; j < ITERS; ++j) {
    int row = j * (NTHR / 16) + r0;
    const float4 v = *reinterpret_cast<const float4*>(src + (size_t)row * ld + c);
    bf16x4 b;
    b[0] = (bf16)v.x; b[1] = (bf16)v.y; b[2] = (bf16)v.z; b[3] = (bf16)v.w;
    *reinterpret_cast<bf16x4*>(dst + swz(row, c)) = b;
  }
}

// ---- staging: global bf16 [ROWS][ld] -> bf16 LDS tile [ROWS][64] ----
template<int ROWS, int NTHR>
__device__ __forceinline__ void stage_bf16(const bf16* __restrict__ src, int ld,
                                           bf16* dst, int tid) {
  constexpr int ITERS = (ROWS * 8) / NTHR;
  const int r0 = tid >> 3;
  const int c  = (tid & 7) * 8;
  #pragma unroll
  for (int j = 0; j < ITERS; ++j) {
    int row = j * (NTHR / 8) + r0;
    bf16x8 v = *reinterpret_cast<const bf16x8*>(src + (size_t)row * ld + c);
    *reinterpret_cast<bf16x8*>(dst + swz(row, c)) = v;
  }
}

// ---- transpose staging: V[64k][DIM] slice -> VT[64n][64k] bf16 LDS (256 thr) ----
__device__ __forceinline__ void stage_vt_f32(const float* __restrict__ src,
                                             bf16* dst, int tid) {
  const int vn = tid & 63, vk0 = (tid >> 6) * 16;
  #pragma unroll
  for (int j = 0; j < 4; ++j) {
    bf16x4 t;
    #pragma unroll
    for (int i = 0; i < 4; ++i) t[i] = (bf16)src[(size_t)(vk0 + 4 * j + i) * DIM + vn];
    *reinterpret_cast<bf16x4*>(dst + swz(vn, vk0 + 4 * j)) = t;
  }
}
__device__ __forceinline__ void stage_vt_bf16(const bf16* __restrict__ src,
                                              bf16* dst, int tid) {
  const int vn = tid & 63, vk0 = (tid >> 6) * 16;
  #pragma unroll
  for (int j = 0; j < 4; ++j) {
    bf16x4 t;
    #pragma unroll
    for (int i = 0; i < 4; ++i) t[i] = src[(size_t)(vk0 + 4 * j + i) * DIM + vn];
    *reinterpret_cast<bf16x4*>(dst + swz(vn, vk0 + 4 * j)) = t;
  }
}

// ---- wave tile: MF x NF fragments of 16x16, K-depth 64 (2 mfma k-steps) ----
template<int MF, int NF>
__device__ __forceinline__ void mma_tile(const bf16* As, const bf16* Bs,
                                         f32x4 (&acc)[MF][NF], int l, int wm, int wn) {
  const int ar = l & 15;
  const int ak = (l >> 4) * 8;
  bf16x8 a[MF][2], b[NF][2];
  #pragma unroll
  for (int mi = 0; mi < MF; ++mi)
    #pragma unroll
    for (int kk = 0; kk < 2; ++kk)
      a[mi][kk] = *reinterpret_cast<const bf16x8*>(As + swz(wm + mi * 16 + ar, kk * 32 + ak));
  #pragma unroll
  for (int ni = 0; ni < NF; ++ni)
    #pragma unroll
    for (int kk = 0; kk < 2; ++kk)
      b[ni][kk] = *reinterpret_cast<const bf16x8*>(Bs + swz(wn + ni * 16 + ar, kk * 32 + ak));
  #pragma unroll
  for (int kk = 0; kk < 2; ++kk)
    #pragma unroll
    for (int mi = 0; mi < MF; ++mi)
      #pragma unroll
      for (int ni = 0; ni < NF; ++ni)
        acc[mi][ni] = __builtin_amdgcn_mfma_f32_16x16x32_bf16(
            a[mi][kk], b[ni][kk], acc[mi][ni], 0, 0, 0);
}

// ============ Kernel A: q/k/v projections (x @ W^T), 128x128 tiles ============
// grid (48, 8): 48 = 3 weights * 16 n-tiles of 128; 8 m-tiles of 128. 4 waves.
__global__ __launch_bounds__(256) void k_qkv(const float* __restrict__ x,
    const float* __restrict__ wq, const float* __restrict__ wk,
    const float* __restrict__ wv,
    bf16* __restrict__ qb, bf16* __restrict__ kb, bf16* __restrict__ vb) {
  __shared__ bf16 As[128 * 64];
  __shared__ bf16 Bs[128 * 64];
  const int nt = blockIdx.x;
  const int w  = nt >> 4;
  const int nloc = (nt & 15) * 128;
  const float* __restrict__ W = (w == 0) ? wq : (w == 1) ? wk : wv;
  bf16* __restrict__ O = (w == 0) ? qb : (w == 1) ? kb : vb;
  const float osc = (w == 0) ? SCALE : 1.0f;   // fold attention scale into q
  const int m0 = blockIdx.y * 128;
  const int tid = threadIdx.x, l = tid & 63, wid = tid >> 6;
  const int wm = (wid >> 1) * 64, wn = (wid & 1) * 64;
  const float* Ap = x + (size_t)m0 * DIM;
  const float* Bp = W + (size_t)nloc * DIM;
  f32x4 acc[4][4] = {};
  for (int kt = 0; kt < DIM / 64; ++kt) {
    __syncthreads();
    stage_f32<128, 256>(Ap + kt * 64, DIM, As, tid);
    stage_f32<128, 256>(Bp + kt * 64, DIM, Bs, tid);
    __syncthreads();
    mma_tile<4, 4>(As, Bs, acc, l, wm, wn);
  }
  const int rr = (l >> 4) * 4, cc = l & 15;
  #pragma unroll
  for (int mi = 0; mi < 4; ++mi)
    #pragma unroll
    for (int ni = 0; ni < 4; ++ni)
      #pragma unroll
      for (int r = 0; r < 4; ++r) {
        int row = m0 + wm + mi * 16 + rr + r;
        int col = nloc + wn + ni * 16 + cc;
        O[(size_t)row * DIM + col] = (bf16)(acc[mi][ni][r] * osc);
      }
}

// ============ Kernel B: scores = q @ k^T (q pre-scaled), 128x128 tiles ============
// grid (33, 8): nt 0..31 -> k_cache rows (fp32), nt==32 -> k_new (bf16). 4 waves.
__global__ __launch_bounds__(256) void k_scores(const bf16* __restrict__ qb,
    const bf16* __restrict__ kb, const float* __restrict__ kcache,
    float* __restrict__ scores) {
  __shared__ bf16 As[128 * 64];
  __shared__ bf16 Bs[128 * 64];
  const int nt = blockIdx.x;
  const int b  = blockIdx.y;
  const int tid = threadIdx.x, l = tid & 63, wid = tid >> 6;
  const int wm = (wid >> 1) * 64, wn = (wid & 1) * 64;
  const bf16* Q = qb + (size_t)b * BQ * DIM;
  const bool useCache = (nt < 32);
  const float* Bf = kcache + ((size_t)b * KVL + nt * 128) * DIM;
  const bf16*  Bb = kb + (size_t)b * BQ * DIM;
  f32x4 acc[4][4] = {};
  for (int kt = 0; kt < DIM / 64; ++kt) {
    const int k0 = kt * 64;
    __syncthreads();
    stage_bf16<128, 256>(Q + k0, DIM, As, tid);
    if (useCache) stage_f32<128, 256>(Bf + k0, DIM, Bs, tid);
    else          stage_bf16<128, 256>(Bb + k0, DIM, Bs, tid);
    __syncthreads();
    mma_tile<4, 4>(As, Bs, acc, l, wm, wn);
  }
  const int rr = (l >> 4) * 4, cc = l & 15;
  #pragma unroll
  for (int mi = 0; mi < 4; ++mi)
    #pragma unroll
    for (int ni = 0; ni < 4; ++ni)
      #pragma unroll
      for (int r = 0; r < 4; ++r) {
        int row = wm + mi * 16 + rr + r;
        int col = nt * 128 + wn + ni * 16 + cc;
        scores[((size_t)b * BQ + row) * KVT + col] = acc[mi][ni][r];
      }
}

// ================= Kernel C: row softmax -> bf16 attn =================
__global__ __launch_bounds__(256) void k_softmax(const float* __restrict__ scores,
                                                 bf16* __restrict__ attn) {
  __shared__ float s[KVT];
  __shared__ float red[8];
  const int row = blockIdx.x;           // 0..1023
  const int tid = threadIdx.x;
  const size_t base = (size_t)row * KVT;
  float lm = -1e30f;
  for (int i = tid; i < KVT; i += 256) {
    float v = scores[base + i];
    s[i] = v;
    lm = fmaxf(lm, v);
  }
  #pragma unroll
  for (int off = 32; off >= 1; off >>= 1) lm = fmaxf(lm, __shfl_xor(lm, off, 64));
  if ((tid & 63) == 0) red[tid >> 6] = lm;
  __syncthreads();
  const float m = fmaxf(fmaxf(red[0], red[1]), fmaxf(red[2], red[3]));
  float ls = 0.f;
  for (int i = tid; i < KVT; i += 256) {
    float e = __expf(s[i] - m);
    s[i] = e;
    ls += e;
  }
  #pragma unroll
  for (int off = 32; off >= 1; off >>= 1) ls += __shfl_xor(ls, off, 64);
  if ((tid & 63) == 0) red[4 + (tid >> 6)] = ls;
  __syncthreads();
  const float inv = 1.f / (red[4] + red[5] + red[6] + red[7]);
  for (int i = tid; i < KVT; i += 256) attn[base + i] = (bf16)(s[i] * inv);
}

// ============ Kernel D: out = attn @ V, 128x64 tiles, K=4224 ============
// grid (32, 8). kt<64 -> v_cache (fp32), else v_new (bf16). 4 waves of 64x32.
__global__ __launch_bounds__(256) void k_pv(const bf16* __restrict__ attn,
    const float* __restrict__ vcache, const bf16* __restrict__ vb,
    bf16* __restrict__ ob) {
  __shared__ bf16 As[128 * 64];
  __shared__ bf16 VT[64 * 64];
  const int n0 = blockIdx.x * 64;
  const int b  = blockIdx.y;
  const int tid = threadIdx.x, l = tid & 63, wid = tid >> 6;
  const int wm = (wid >> 1) * 64, wn = (wid & 1) * 32;
  const bf16* Ap = attn + (size_t)b * BQ * KVT;
  f32x4 acc[4][2] = {};
  for (int kt = 0; kt < KVT / 64; ++kt) {
    const int k0 = kt * 64;
    __syncthreads();
    stage_bf16<128, 256>(Ap + k0, KVT, As, tid);
    if (kt < 64) stage_vt_f32(vcache + ((size_t)b * KVL + k0) * DIM + n0, VT, tid);
    else         stage_vt_bf16(vb + ((size_t)b * BQ + (k0 - KVL)) * DIM + n0, VT, tid);
    __syncthreads();
    mma_tile<4, 2>(As, VT, acc, l, wm, wn);
  }
  const int rr = (l >> 4) * 4, cc = l & 15;
  #pragma unroll
  for (int mi = 0; mi < 4; ++mi)
    #pragma unroll
    for (int ni = 0; ni < 2; ++ni)
      #pragma unroll
      for (int r = 0; r < 4; ++r) {
        int row = wm + mi * 16 + rr + r;
        int col = n0 + wn + ni * 16 + cc;
        ob[((size_t)b * BQ + row) * DIM + col] = (bf16)acc[mi][ni][r];
      }
}

// ============ Kernel E: final = out @ wo^T (fp32), 128x64 tiles ============
// grid (32, 8): 32 n-tiles of 64, 8 m-tiles of 128. 4 waves of 64x32.
__global__ __launch_bounds__(256) void k_oproj(const bf16* __restrict__ ob,
    const float* __restrict__ wo, float* __restrict__ out) {
  __shared__ bf16 As[128 * 64];
  __shared__ bf16 Bs[64 * 64];
  const int n0 = blockIdx.x * 64;
  const int m0 = blockIdx.y * 128;
  const int tid = threadIdx.x, l = tid & 63, wid = tid >> 6;
  const int wm = (wid >> 1) * 64, wn = (wid & 1) * 32;
  const bf16*  Apb = ob + (size_t)m0 * DIM;
  const float* Bpf = wo + (size_t)n0 * DIM;
  f32x4 acc[4][2] = {};
  for (int kt = 0; kt < DIM / 64; ++kt) {
    const int k0 = kt * 64;
    __syncthreads();
    stage_bf16<128, 256>(Apb + k0, DIM, As, tid);
    stage_f32<64, 256>(Bpf + k0, DIM, Bs, tid);
    __syncthreads();
    mma_tile<4, 2>(As, Bs, acc, l, wm, wn);
  }
  const int rr = (l >> 4) * 4, cc = l & 15;
  #pragma unroll
  for (int mi = 0; mi < 4; ++mi)
    #pragma unroll
    for (int ni = 0; ni < 2; ++ni)
      #pragma unroll
      for (int r = 0; r < 4; ++r) {
        int row = m0 + wm + mi * 16 + rr + r;
        int col = n0 + wn + ni * 16 + cc;
        out[(size_t)row * DIM + col] = acc[mi][ni][r];
      }
}

extern "C" void kernel_launch(void* const* d_in, const int* in_sizes, int n_in,
                              void* d_out, int out_size, void* d_ws, size_t ws_size,
                              hipStream_t stream) {
  const float* x      = (const float*)d_in[0];
  // d_in[1] = mask (unused by the reference forward)
  const float* kcache = (const float*)d_in[2];
  const float* vcache = (const float*)d_in[3];
  const float* wq     = (const float*)d_in[4];
  const float* wk     = (const float*)d_in[5];
  const float* wv     = (const float*)d_in[6];
  const float* wo     = (const float*)d_in[7];
  float* out = (float*)d_out;

  char* ws = (char*)d_ws;
  bf16*  qb     = (bf16*)(ws + 0);                    //  4 MB  [1024][2048]
  bf16*  kb     = (bf16*)(ws + 4194304);              //  4 MB
  bf16*  vb     = (bf16*)(ws + 8388608);              //  4 MB
  float* scores = (float*)(ws + 12582912);            // 17.3 MB [1024][4224]
  bf16*  attnb  = (bf16*)(ws + 29884416);             //  8.65 MB
  bf16*  obuf   = (bf16*)(ws + 38535168);             //  4 MB

  k_qkv<<<dim3(48, 8), 256, 0, stream>>>(x, wq, wk, wv, qb, kb, vb);
  k_scores<<<dim3(33, 8), 256, 0, stream>>>(qb, kb, kcache, scores);
  k_softmax<<<dim3(1024), 256, 0, stream>>>(scores, attnb);
  k_pv<<<dim3(32, 8), 256, 0, stream>>>(attnb, vcache, vb, obuf);
  k_oproj<<<dim3(32, 8), 256, 0, stream>>>(obuf, wo, out);
}

// Round 4
// 245.630 us; speedup vs baseline: 1.3578x; 1.3578x over previous
//
#include <hip/hip_runtime.h>

typedef __bf16 bf16;
typedef __bf16 bf16x4 __attribute__((ext_vector_type(4)));
typedef __bf16 bf16x8 __attribute__((ext_vector_type(8)));
typedef float f32x4 __attribute__((ext_vector_type(4)));

#define DIM   2048
#define BQ    128
#define KVL   4096
#define KVT   4224   // KV_LEN + Q_LEN
#define SCALE 0.022097086912079608f  // 1/sqrt(2048)

// Swizzled element offset inside a [ROWS][64]-bf16 LDS tile (128B rows).
__device__ __forceinline__ int swz(int row, int col) {
  return row * 64 + (col ^ ((row & 7) << 3));
}

// ---------- register prefetch of a [R][64] bf16 tile (src bf16) ----------
template<int R>
struct PB {
  bf16x8 v[R / 32];
  __device__ __forceinline__ void load(const bf16* __restrict__ src, int ld, int tid) {
    const int r0 = tid >> 3, c = (tid & 7) * 8;
    #pragma unroll
    for (int j = 0; j < R / 32; ++j)
      v[j] = *reinterpret_cast<const bf16x8*>(src + (size_t)(j * 32 + r0) * ld + c);
  }
  __device__ __forceinline__ void write(bf16* dst, int tid) {
    const int r0 = tid >> 3, c = (tid & 7) * 8;
    #pragma unroll
    for (int j = 0; j < R / 32; ++j)
      *reinterpret_cast<bf16x8*>(dst + swz(j * 32 + r0, c)) = v[j];
  }
};

// ---------- register prefetch of a [64][64] tile from f32 OR bf16 src ----------
struct PU64 {
  float4 v[4];
  int r0, c;
  __device__ __forceinline__ void init(int tid) { r0 = tid >> 4; c = (tid & 15) * 4; }
  __device__ __forceinline__ void loadF(const float* __restrict__ src, int ld) {
    #pragma unroll
    for (int j = 0; j < 4; ++j)
      v[j] = *reinterpret_cast<const float4*>(src + (size_t)(j * 16 + r0) * ld + c);
  }
  __device__ __forceinline__ void loadB(const bf16* __restrict__ src, int ld) {
    #pragma unroll
    for (int j = 0; j < 4; ++j) {
      bf16x4 t = *reinterpret_cast<const bf16x4*>(src + (size_t)(j * 16 + r0) * ld + c);
      v[j].x = (float)t[0]; v[j].y = (float)t[1]; v[j].z = (float)t[2]; v[j].w = (float)t[3];
    }
  }
  __device__ __forceinline__ void write(bf16* dst) {
    #pragma unroll
    for (int j = 0; j < 4; ++j) {
      bf16x4 b;
      b[0] = (bf16)v[j].x; b[1] = (bf16)v[j].y; b[2] = (bf16)v[j].z; b[3] = (bf16)v[j].w;
      *reinterpret_cast<bf16x4*>(dst + swz(j * 16 + r0, c)) = b;
    }
  }
};

// ---------- transpose prefetch: V[64k][DIM] slice -> VT[64n][64k] ----------
struct PVT {
  float v[16];
  int vn, vk0;
  __device__ __forceinline__ void init(int tid) { vn = tid & 63; vk0 = (tid >> 6) * 16; }
  __device__ __forceinline__ void loadF(const float* __restrict__ src) {
    #pragma unroll
    for (int i = 0; i < 16; ++i) v[i] = src[(size_t)(vk0 + i) * DIM + vn];
  }
  __device__ __forceinline__ void loadB(const bf16* __restrict__ src) {
    #pragma unroll
    for (int i = 0; i < 16; ++i) v[i] = (float)src[(size_t)(vk0 + i) * DIM + vn];
  }
  __device__ __forceinline__ void write(bf16* dst) {
    #pragma unroll
    for (int j = 0; j < 4; ++j) {
      bf16x4 t;
      #pragma unroll
      for (int i = 0; i < 4; ++i) t[i] = (bf16)v[4 * j + i];
      *reinterpret_cast<bf16x4*>(dst + swz(vn, vk0 + 4 * j)) = t;
    }
  }
};

// ---- wave tile: MF x NF fragments of 16x16, K-depth 64 (2 mfma k-steps) ----
template<int MF, int NF>
__device__ __forceinline__ void mma_tile(const bf16* As, const bf16* Bs,
                                         f32x4 (&acc)[MF][NF], int l, int wm, int wn) {
  const int ar = l & 15;
  const int ak = (l >> 4) * 8;
  bf16x8 a[MF][2], b[NF][2];
  #pragma unroll
  for (int mi = 0; mi < MF; ++mi)
    #pragma unroll
    for (int kk = 0; kk < 2; ++kk)
      a[mi][kk] = *reinterpret_cast<const bf16x8*>(As + swz(wm + mi * 16 + ar, kk * 32 + ak));
  #pragma unroll
  for (int ni = 0; ni < NF; ++ni)
    #pragma unroll
    for (int kk = 0; kk < 2; ++kk)
      b[ni][kk] = *reinterpret_cast<const bf16x8*>(Bs + swz(wn + ni * 16 + ar, kk * 32 + ak));
  #pragma unroll
  for (int kk = 0; kk < 2; ++kk)
    #pragma unroll
    for (int mi = 0; mi < MF; ++mi)
      #pragma unroll
      for (int ni = 0; ni < NF; ++ni)
        acc[mi][ni] = __builtin_amdgcn_mfma_f32_16x16x32_bf16(
            a[mi][kk], b[ni][kk], acc[mi][ni], 0, 0, 0);
}

// ============ Kernel 0: f32 -> bf16 conversion (x + 4 weights) ============
// grid (2048, 5), 256 thr, 8 elems/thread. seg 1 (wq) folds the attn scale.
__global__ __launch_bounds__(256) void k_cvt(const float* __restrict__ x,
    const float* __restrict__ wq, const float* __restrict__ wk,
    const float* __restrict__ wv, const float* __restrict__ wo,
    bf16* __restrict__ xb, bf16* __restrict__ wb) {
  const int seg = blockIdx.y;
  const float* src; bf16* dst; int n; float sc = 1.0f;
  if (seg == 0)      { src = x;  dst = xb;            n = 1024 * DIM; }
  else if (seg == 1) { src = wq; dst = wb;            n = DIM * DIM; sc = SCALE; }
  else if (seg == 2) { src = wk; dst = wb + 1 * DIM * DIM; n = DIM * DIM; }
  else if (seg == 3) { src = wv; dst = wb + 2 * DIM * DIM; n = DIM * DIM; }
  else               { src = wo; dst = wb + 3 * DIM * DIM; n = DIM * DIM; }
  const int i0 = (blockIdx.x * 256 + threadIdx.x) * 8;
  if (i0 >= n) return;
  #pragma unroll
  for (int h = 0; h < 2; ++h) {
    float4 v = *reinterpret_cast<const float4*>(src + i0 + 4 * h);
    bf16x4 b;
    b[0] = (bf16)(v.x * sc); b[1] = (bf16)(v.y * sc);
    b[2] = (bf16)(v.z * sc); b[3] = (bf16)(v.w * sc);
    *reinterpret_cast<bf16x4*>(dst + i0 + 4 * h) = b;
  }
}

// ============ Kernel A: q/k/v projections (xb @ wb^T), 128x64 tiles ============
// grid (96, 8): 96 row-blocks of 64 over stacked [6144][2048] weights.
__global__ __launch_bounds__(256) void k_qkv(const bf16* __restrict__ xb,
    const bf16* __restrict__ wb,
    bf16* __restrict__ qb, bf16* __restrict__ kb, bf16* __restrict__ vb) {
  __shared__ bf16 As[2][128 * 64];
  __shared__ bf16 Bs[2][64 * 64];
  const int nt = blockIdx.x;
  const int w  = nt >> 5;
  const int col0 = (nt & 31) * 64;
  bf16* __restrict__ O = (w == 0) ? qb : (w == 1) ? kb : vb;
  const int m0 = blockIdx.y * 128;
  const int tid = threadIdx.x, l = tid & 63, wid = tid >> 6;
  const int wm = (wid >> 1) * 64, wn = (wid & 1) * 32;
  const bf16* Ap = xb + (size_t)m0 * DIM;
  const bf16* Bp = wb + (size_t)nt * 64 * DIM;
  PB<128> pa; PB<64> pbb;
  f32x4 acc[4][2] = {};
  pa.load(Ap, DIM, tid); pbb.load(Bp, DIM, tid);
  pa.write(As[0], tid);  pbb.write(Bs[0], tid);
  int cur = 0;
  constexpr int NT = DIM / 64;
  for (int kt = 0; kt < NT; ++kt) {
    if (kt + 1 < NT) { pa.load(Ap + (kt + 1) * 64, DIM, tid); pbb.load(Bp + (kt + 1) * 64, DIM, tid); }
    __syncthreads();
    mma_tile<4, 2>(As[cur], Bs[cur], acc, l, wm, wn);
    if (kt + 1 < NT) { pa.write(As[cur ^ 1], tid); pbb.write(Bs[cur ^ 1], tid); }
    cur ^= 1;
  }
  const int rr = (l >> 4) * 4, cc = l & 15;
  #pragma unroll
  for (int mi = 0; mi < 4; ++mi)
    #pragma unroll
    for (int ni = 0; ni < 2; ++ni)
      #pragma unroll
      for (int r = 0; r < 4; ++r)
        O[(size_t)(m0 + wm + mi * 16 + rr + r) * DIM + col0 + wn + ni * 16 + cc] =
            (bf16)acc[mi][ni][r];
}

// ============ Kernel B: scores = q @ k^T (q pre-scaled), 128x64 tiles ============
// grid (66, 8): nt 0..63 -> k_cache (fp32), 64..65 -> k_new (bf16).
__global__ __launch_bounds__(256) void k_scores(const bf16* __restrict__ qb,
    const bf16* __restrict__ kb, const float* __restrict__ kcache,
    float* __restrict__ scores) {
  __shared__ bf16 As[2][128 * 64];
  __shared__ bf16 Bs[2][64 * 64];
  const int nt = blockIdx.x;
  const int b  = blockIdx.y;
  const int tid = threadIdx.x, l = tid & 63, wid = tid >> 6;
  const int wm = (wid >> 1) * 64, wn = (wid & 1) * 32;
  const bf16* Q = qb + (size_t)b * BQ * DIM;
  const bool useCache = (nt < 64);
  const float* Bf = kcache + ((size_t)b * KVL + nt * 64) * DIM;
  const bf16*  Bb = kb + ((size_t)b * BQ + (nt - 64) * 64) * DIM;
  PB<128> pa; PU64 pu; pu.init(tid);
  f32x4 acc[4][2] = {};
  pa.load(Q, DIM, tid);
  if (useCache) pu.loadF(Bf, DIM); else pu.loadB(Bb, DIM);
  pa.write(As[0], tid); pu.write(Bs[0]);
  int cur = 0;
  constexpr int NT = DIM / 64;
  for (int kt = 0; kt < NT; ++kt) {
    if (kt + 1 < NT) {
      pa.load(Q + (kt + 1) * 64, DIM, tid);
      if (useCache) pu.loadF(Bf + (kt + 1) * 64, DIM); else pu.loadB(Bb + (kt + 1) * 64, DIM);
    }
    __syncthreads();
    mma_tile<4, 2>(As[cur], Bs[cur], acc, l, wm, wn);
    if (kt + 1 < NT) { pa.write(As[cur ^ 1], tid); pu.write(Bs[cur ^ 1]); }
    cur ^= 1;
  }
  const int rr = (l >> 4) * 4, cc = l & 15;
  #pragma unroll
  for (int mi = 0; mi < 4; ++mi)
    #pragma unroll
    for (int ni = 0; ni < 2; ++ni)
      #pragma unroll
      for (int r = 0; r < 4; ++r)
        scores[((size_t)b * BQ + wm + mi * 16 + rr + r) * KVT + nt * 64 + wn + ni * 16 + cc] =
            acc[mi][ni][r];
}

// ================= Kernel C: row softmax -> bf16 attn =================
__global__ __launch_bounds__(256) void k_softmax(const float* __restrict__ scores,
                                                 bf16* __restrict__ attn) {
  __shared__ float s[KVT];
  __shared__ float red[8];
  const int row = blockIdx.x;
  const int tid = threadIdx.x;
  const size_t base = (size_t)row * KVT;
  float lm = -1e30f;
  for (int i = tid; i < KVT; i += 256) {
    float v = scores[base + i];
    s[i] = v;
    lm = fmaxf(lm, v);
  }
  #pragma unroll
  for (int off = 32; off >= 1; off >>= 1) lm = fmaxf(lm, __shfl_xor(lm, off, 64));
  if ((tid & 63) == 0) red[tid >> 6] = lm;
  __syncthreads();
  const float m = fmaxf(fmaxf(red[0], red[1]), fmaxf(red[2], red[3]));
  float ls = 0.f;
  for (int i = tid; i < KVT; i += 256) {
    float e = __expf(s[i] - m);
    s[i] = e;
    ls += e;
  }
  #pragma unroll
  for (int off = 32; off >= 1; off >>= 1) ls += __shfl_xor(ls, off, 64);
  if ((tid & 63) == 0) red[4 + (tid >> 6)] = ls;
  __syncthreads();
  const float inv = 1.f / (red[4] + red[5] + red[6] + red[7]);
  for (int i = tid; i < KVT; i += 256) attn[base + i] = (bf16)(s[i] * inv);
}

// ============ Kernel D: partial out = attn @ V over a KV chunk ============
// grid (32, 8, 2): 32 n-tiles of 64, 8 batches, 2 KV-chunks of 2112 (33 steps).
__global__ __launch_bounds__(256) void k_pv(const bf16* __restrict__ attn,
    const float* __restrict__ vcache, const bf16* __restrict__ vb,
    float* __restrict__ pp) {
  __shared__ bf16 As[2][128 * 64];
  __shared__ bf16 VT[2][64 * 64];
  const int n0 = blockIdx.x * 64;
  const int b  = blockIdx.y;
  const int c  = blockIdx.z;
  const int tid = threadIdx.x, l = tid & 63, wid = tid >> 6;
  const int wm = (wid >> 1) * 64, wn = (wid & 1) * 32;
  const bf16* Ap = attn + (size_t)b * BQ * KVT + c * 2112;
  PB<128> pa; PVT pv; pv.init(tid);
  f32x4 acc[4][2] = {};
  auto loadV = [&](int lk) {
    const int grow = c * 2112 + lk * 64;
    if (grow < KVL) pv.loadF(vcache + ((size_t)b * KVL + grow) * DIM + n0);
    else            pv.loadB(vb + ((size_t)b * BQ + (grow - KVL)) * DIM + n0);
  };
  pa.load(Ap, KVT, tid); loadV(0);
  pa.write(As[0], tid);  pv.write(VT[0]);
  int cur = 0;
  constexpr int NT = 33;
  for (int kt = 0; kt < NT; ++kt) {
    if (kt + 1 < NT) { pa.load(Ap + (kt + 1) * 64, KVT, tid); loadV(kt + 1); }
    __syncthreads();
    mma_tile<4, 2>(As[cur], VT[cur], acc, l, wm, wn);
    if (kt + 1 < NT) { pa.write(As[cur ^ 1], tid); pv.write(VT[cur ^ 1]); }
    cur ^= 1;
  }
  float* P = pp + (size_t)c * 1024 * DIM;
  const int rr = (l >> 4) * 4, cc = l & 15;
  #pragma unroll
  for (int mi = 0; mi < 4; ++mi)
    #pragma unroll
    for (int ni = 0; ni < 2; ++ni)
      #pragma unroll
      for (int r = 0; r < 4; ++r)
        P[((size_t)b * BQ + wm + mi * 16 + rr + r) * DIM + n0 + wn + ni * 16 + cc] =
            acc[mi][ni][r];
}

// ============ combine: obuf = bf16(pp0 + pp1) ============
__global__ __launch_bounds__(256) void k_pvcomb(const float* __restrict__ pp,
                                                bf16* __restrict__ ob) {
  const int i0 = (blockIdx.x * 256 + threadIdx.x) * 4;
  float4 a = *reinterpret_cast<const float4*>(pp + i0);
  float4 b = *reinterpret_cast<const float4*>(pp + 1024 * DIM + i0);
  bf16x4 o;
  o[0] = (bf16)(a.x + b.x); o[1] = (bf16)(a.y + b.y);
  o[2] = (bf16)(a.z + b.z); o[3] = (bf16)(a.w + b.w);
  *reinterpret_cast<bf16x4*>(ob + i0) = o;
}

// ============ Kernel E: partial final = obuf @ wo'^T over a K half ============
// grid (32, 8, 2): 32 n-tiles of 64, 8 m-tiles of 128, 2 K-halves (16 steps).
__global__ __launch_bounds__(256) void k_oproj(const bf16* __restrict__ ob,
    const bf16* __restrict__ wob, float* __restrict__ po) {
  __shared__ bf16 As[2][128 * 64];
  __shared__ bf16 Bs[2][64 * 64];
  const int n0 = blockIdx.x * 64;
  const int m0 = blockIdx.y * 128;
  const int kz = blockIdx.z;
  const int tid = threadIdx.x, l = tid & 63, wid = tid >> 6;
  const int wm = (wid >> 1) * 64, wn = (wid & 1) * 32;
  const bf16* Ap = ob  + (size_t)m0 * DIM + kz * 1024;
  const bf16* Bp = wob + (size_t)n0 * DIM + kz * 1024;
  PB<128> pa; PB<64> pbb;
  f32x4 acc[4][2] = {};
  pa.load(Ap, DIM, tid); pbb.load(Bp, DIM, tid);
  pa.write(As[0], tid);  pbb.write(Bs[0], tid);
  int cur = 0;
  constexpr int NT = 16;
  for (int kt = 0; kt < NT; ++kt) {
    if (kt + 1 < NT) { pa.load(Ap + (kt + 1) * 64, DIM, tid); pbb.load(Bp + (kt + 1) * 64, DIM, tid); }
    __syncthreads();
    mma_tile<4, 2>(As[cur], Bs[cur], acc, l, wm, wn);
    if (kt + 1 < NT) { pa.write(As[cur ^ 1], tid); pbb.write(Bs[cur ^ 1], tid); }
    cur ^= 1;
  }
  float* P = po + (size_t)kz * 1024 * DIM;
  const int rr = (l >> 4) * 4, cc = l & 15;
  #pragma unroll
  for (int mi = 0; mi < 4; ++mi)
    #pragma unroll
    for (int ni = 0; ni < 2; ++ni)
      #pragma unroll
      for (int r = 0; r < 4; ++r)
        P[(size_t)(m0 + wm + mi * 16 + rr + r) * DIM + n0 + wn + ni * 16 + cc] =
            acc[mi][ni][r];
}

// ============ combine: out = po0 + po1 (fp32) ============
__global__ __launch_bounds__(256) void k_ocomb(const float* __restrict__ po,
                                               float* __restrict__ out) {
  const int i0 = (blockIdx.x * 256 + threadIdx.x) * 4;
  float4 a = *reinterpret_cast<const float4*>(po + i0);
  float4 b = *reinterpret_cast<const float4*>(po + 1024 * DIM + i0);
  float4 o = {a.x + b.x, a.y + b.y, a.z + b.z, a.w + b.w};
  *reinterpret_cast<float4*>(out + i0) = o;
}

extern "C" void kernel_launch(void* const* d_in, const int* in_sizes, int n_in,
                              void* d_out, int out_size, void* d_ws, size_t ws_size,
                              hipStream_t stream) {
  const float* x      = (const float*)d_in[0];
  // d_in[1] = mask (unused by the reference forward)
  const float* kcache = (const float*)d_in[2];
  const float* vcache = (const float*)d_in[3];
  const float* wq     = (const float*)d_in[4];
  const float* wk     = (const float*)d_in[5];
  const float* wv     = (const float*)d_in[6];
  const float* wo     = (const float*)d_in[7];
  float* out = (float*)d_out;

  char* ws = (char*)d_ws;                       // ws_size ~1 GB (per poison fills)
  bf16*  xb     = (bf16*)(ws + 0);              //  4.19 MB [1024][2048]
  bf16*  wb     = (bf16*)(ws + 4194304);        // 33.55 MB [4*2048][2048] (wq',wk',wv',wo')
  bf16*  qb     = (bf16*)(ws + 37748736);       //  4.19 MB
  bf16*  kb     = (bf16*)(ws + 41943040);       //  4.19 MB
  bf16*  vb     = (bf16*)(ws + 46137344);       //  4.19 MB
  float* scores = (float*)(ws + 50331648);      // 17.30 MB [1024][4224]; later pp/po (16.78 MB)
  bf16*  attnb  = (bf16*)(ws + 67633152);       //  8.65 MB
  bf16*  obuf   = (bf16*)(ws + 76283904);       //  4.19 MB
  float* pp     = scores;                       // 2x [1024][2048] f32 partials (reuse)
  bf16*  wob    = wb + (size_t)3 * DIM * DIM;

  k_cvt<<<dim3(2048, 5), 256, 0, stream>>>(x, wq, wk, wv, wo, xb, wb);
  k_qkv<<<dim3(96, 8), 256, 0, stream>>>(xb, wb, qb, kb, vb);
  k_scores<<<dim3(66, 8), 256, 0, stream>>>(qb, kb, kcache, scores);
  k_softmax<<<dim3(1024), 256, 0, stream>>>(scores, attnb);
  k_pv<<<dim3(32, 8, 2), 256, 0, stream>>>(attnb, vcache, vb, pp);
  k_pvcomb<<<dim3(2048), 256, 0, stream>>>(pp, obuf);
  k_oproj<<<dim3(32, 8, 2), 256, 0, stream>>>(obuf, wob, pp);
  k_ocomb<<<dim3(2048), 256, 0, stream>>>(pp, out);
}